// Round 1
// baseline (190.521 us; speedup 1.0000x reference)
//
#include <hip/hip_runtime.h>

#define B 32
#define E 256
#define N 64
#define KV 100
#define QD 768

// ---------------------------------------------------------------------------
// Prep: blocks 0..31 -> Qk[b][j] = 0.1 * sum_i tanh(q[b]@W_q[i]+b_q[i]) * W_kv[i][j]
//       block 32     -> W_vT[d][i] = W_v[i][d]   (for coalesced proj reads)
// ---------------------------------------------------------------------------
__global__ __launch_bounds__(256) void prep_kernel(
    const float* __restrict__ q,      // [B, QD]
    const float* __restrict__ W_q,    // [KV, QD]
    const float* __restrict__ b_q,    // [KV]
    const float* __restrict__ W_kv,   // [KV, KV]
    const float* __restrict__ W_v,    // [KV, KV]
    float* __restrict__ Qk,           // ws: [B, KV]
    float* __restrict__ W_vT)         // ws: [KV, KV]
{
    const int blk = blockIdx.x;
    const int tid = threadIdx.x;

    if (blk == B) {
        for (int idx = tid; idx < KV * KV; idx += 256) {
            int d = idx / KV, i = idx % KV;
            W_vT[idx] = W_v[i * KV + d];
        }
        return;
    }

    __shared__ float q_lds[QD];
    __shared__ float Qp_lds[KV];
    const int b = blk;

    for (int i = tid; i < QD; i += 256) q_lds[i] = q[b * QD + i];
    __syncthreads();

    // Qp[i] = tanh(dot(q[b], W_q[i]) + b_q[i]); 2 threads per output
    const int i = tid >> 1, h = tid & 1;
    if (i < KV) {
        float acc = 0.f;
        const float* wrow = W_q + i * QD + h * (QD / 2);
        const float* qrow = q_lds + h * (QD / 2);
        #pragma unroll 8
        for (int d = 0; d < QD / 2; d++) acc += qrow[d] * wrow[d];
        acc += __shfl_xor(acc, 1);
        if (h == 0) Qp_lds[i] = tanhf(acc + b_q[i]);
    }
    __syncthreads();

    // Qk[b][j] = (1/sqrt(KV)) * sum_i Qp[i] * W_kv[i][j]
    if (tid < KV) {
        float acc = 0.f;
        #pragma unroll 4
        for (int ii = 0; ii < KV; ii++) acc += Qp_lds[ii] * W_kv[ii * KV + tid];
        Qk[b * KV + tid] = acc * 0.1f;   // 1/sqrt(100)
    }
}

// ---------------------------------------------------------------------------
// Main: one block per (b,e). Stream k,v tiles once; everything else in LDS.
// ---------------------------------------------------------------------------
__global__ __launch_bounds__(256) void attn_kernel(
    const float* __restrict__ k,    // [B,E,N,KV]
    const float* __restrict__ v,    // [B,E,N,KV]
    const float* __restrict__ Qk,   // [B,KV] (pre-scaled)
    const float* __restrict__ W_vT, // [KV,KV] transposed
    float* __restrict__ out)        // [B,E,KV]
{
    __shared__ float k_lds[N * KV];   // 25.6 KB
    __shared__ float v_lds[N * KV];   // 25.6 KB
    __shared__ float qk_lds[KV];
    __shared__ float att_lds[N];
    __shared__ float agg_lds[KV];

    const int tid = threadIdx.x;
    const int be  = blockIdx.x;       // 0..B*E-1
    const int b   = be >> 8;          // /E

    const float4* kg = (const float4*)(k + (size_t)be * (N * KV));
    const float4* vg = (const float4*)(v + (size_t)be * (N * KV));
    float4* kl = (float4*)k_lds;
    float4* vl = (float4*)v_lds;
    // contiguous float4 staging: perfectly coalesced, tiles read exactly once
    #pragma unroll
    for (int j = tid; j < (N * KV) / 4; j += 256) kl[j] = kg[j];
    #pragma unroll
    for (int j = tid; j < (N * KV) / 4; j += 256) vl[j] = vg[j];
    if (tid < KV) qk_lds[tid] = Qk[b * KV + tid];
    __syncthreads();

    // att[n] = Qk . k[n,:]   (4 lanes per row; 2-way LDS aliasing = free)
    {
        const int n = tid >> 2, sub = tid & 3;
        float acc = 0.f;
        #pragma unroll
        for (int d = sub; d < KV; d += 4)
            acc += qk_lds[d] * k_lds[n * KV + d];
        acc += __shfl_xor(acc, 1);
        acc += __shfl_xor(acc, 2);
        if (sub == 0) {
            float a = acc;                      // already scaled by 1/sqrt(KV)
            if (a == 0.0f) a = -10000.0f;       // masked_fill(att==0, -1e4)
            a = (a > 0.0f) ? a : 0.01f * a;     // leaky_relu
            att_lds[n] = a;
        }
    }
    __syncthreads();

    // softmax over N=64 in wave 0
    if (tid < 64) {
        float x = att_lds[tid];
        float m = x;
        #pragma unroll
        for (int o = 32; o; o >>= 1) m = fmaxf(m, __shfl_xor(m, o));
        float e = __expf(x - m);
        float s = e;
        #pragma unroll
        for (int o = 32; o; o >>= 1) s += __shfl_xor(s, o);
        float r = e / s;
        if (r == 0.015625f) r = 0.0f;           // masked_fill(att==1/N, 0)
        att_lds[tid] = r;
    }
    __syncthreads();

    // agg[d] = sum_n att[n] * v[n,d]  (att broadcast; v column reads conflict-free)
    if (tid < KV) {
        float acc = 0.f;
        #pragma unroll 8
        for (int nn = 0; nn < N; nn++)
            acc += att_lds[nn] * v_lds[nn * KV + tid];
        agg_lds[tid] = acc;
    }
    __syncthreads();

    // out[be][i] = sum_d agg[d] * W_vT[d][i]   (W_vT is L2-resident, coalesced)
    if (tid < KV) {
        float acc = 0.f;
        #pragma unroll 4
        for (int d = 0; d < KV; d++)
            acc += agg_lds[d] * W_vT[d * KV + tid];
        out[(size_t)be * KV + tid] = acc;
    }
}

extern "C" void kernel_launch(void* const* d_in, const int* in_sizes, int n_in,
                              void* d_out, int out_size, void* d_ws, size_t ws_size,
                              hipStream_t stream) {
    // setup_inputs order: input_ent, q, k, v, W_q, b_q, W_kv, W_v
    const float* q    = (const float*)d_in[1];
    const float* k    = (const float*)d_in[2];
    const float* v    = (const float*)d_in[3];
    const float* W_q  = (const float*)d_in[4];
    const float* b_q  = (const float*)d_in[5];
    const float* W_kv = (const float*)d_in[6];
    const float* W_v  = (const float*)d_in[7];
    float* out  = (float*)d_out;

    float* Qk   = (float*)d_ws;          // B*KV   = 3200 floats
    float* W_vT = Qk + B * KV;           // KV*KV  = 10000 floats

    prep_kernel<<<B + 1, 256, 0, stream>>>(q, W_q, b_q, W_kv, W_v, Qk, W_vT);
    attn_kernel<<<B * E, 256, 0, stream>>>(k, v, Qk, W_vT, out);
}

// Round 2
// 113.616 us; speedup vs baseline: 1.6769x; 1.6769x over previous
//
#include <hip/hip_runtime.h>

#define B 32
#define E 256
#define N 64
#define KV 100
#define QD 768

// ---------------------------------------------------------------------------
// Prep: blocks 0..31 -> Qk[b][j] = 0.1 * sum_i tanh(q[b]@W_q[i]+b_q[i]) * W_kv[i][j]
//       block 32     -> W_vT[d][i] = W_v[i][d]   (for coalesced proj reads)
// ---------------------------------------------------------------------------
__global__ __launch_bounds__(256) void prep_kernel(
    const float* __restrict__ q,      // [B, QD]
    const float* __restrict__ W_q,    // [KV, QD]
    const float* __restrict__ b_q,    // [KV]
    const float* __restrict__ W_kv,   // [KV, KV]
    const float* __restrict__ W_v,    // [KV, KV]
    float* __restrict__ Qk,           // ws: [B, KV]
    float* __restrict__ W_vT)         // ws: [KV, KV]
{
    const int blk = blockIdx.x;
    const int tid = threadIdx.x;

    if (blk == B) {
        for (int idx = tid; idx < KV * KV; idx += 256) {
            int d = idx / KV, i = idx % KV;
            W_vT[idx] = W_v[i * KV + d];
        }
        return;
    }

    __shared__ float q_lds[QD];
    __shared__ float Qp_lds[KV];
    const int b = blk;

    for (int i = tid; i < QD; i += 256) q_lds[i] = q[b * QD + i];
    __syncthreads();

    // Qp[i] = tanh(dot(q[b], W_q[i]) + b_q[i]); 2 threads per output
    const int i = tid >> 1, h = tid & 1;
    if (i < KV) {
        float acc = 0.f;
        const float* wrow = W_q + i * QD + h * (QD / 2);
        const float* qrow = q_lds + h * (QD / 2);
        #pragma unroll 8
        for (int d = 0; d < QD / 2; d++) acc += qrow[d] * wrow[d];
        acc += __shfl_xor(acc, 1);
        if (h == 0) Qp_lds[i] = tanhf(acc + b_q[i]);
    }
    __syncthreads();

    // Qk[b][j] = (1/sqrt(KV)) * sum_i Qp[i] * W_kv[i][j]
    if (tid < KV) {
        float acc = 0.f;
        #pragma unroll 4
        for (int ii = 0; ii < KV; ii++) acc += Qp_lds[ii] * W_kv[ii * KV + tid];
        Qk[b * KV + tid] = acc * 0.1f;   // 1/sqrt(100)
    }
}

// ---------------------------------------------------------------------------
// Main: one block per (b,e). NO k/v LDS staging (zero reuse -> stream direct
// from global; ~1.3 KB LDS -> ~7 blocks/CU resident, TLP hides HBM latency).
// ---------------------------------------------------------------------------
__global__ __launch_bounds__(256) void attn_kernel(
    const float* __restrict__ k,    // [B,E,N,KV]
    const float* __restrict__ v,    // [B,E,N,KV]
    const float* __restrict__ Qk,   // [B,KV] (pre-scaled by 1/sqrt(KV))
    const float* __restrict__ W_vT, // [KV,KV] transposed
    float* __restrict__ out)        // [B,E,KV]
{
    __shared__ float att_lds[N];
    __shared__ float part_lds[2][KV];
    __shared__ float agg_lds[KV];

    const int tid = threadIdx.x;
    const int be  = blockIdx.x;       // 0..B*E-1
    const int b   = be >> 8;          // /E

    // ---- scores: 4 lanes per row, float4 direct from global (64B/quad) ----
    {
        const int n = tid >> 2, sub = tid & 3;
        const float4* krow = (const float4*)(k + (size_t)be * (N * KV) + n * KV);
        const float4* qk4  = (const float4*)(Qk + b * KV);   // L1-resident
        float acc = 0.f;
        #pragma unroll
        for (int j = sub; j < KV / 4; j += 4) {
            float4 kk = krow[j];
            float4 qq = qk4[j];
            acc += qq.x * kk.x + qq.y * kk.y + qq.z * kk.z + qq.w * kk.w;
        }
        acc += __shfl_xor(acc, 1);
        acc += __shfl_xor(acc, 2);
        if (sub == 0) {
            float a = acc;                      // already scaled by 1/sqrt(KV)
            if (a == 0.0f) a = -10000.0f;       // masked_fill(att==0, -1e4)
            a = (a > 0.0f) ? a : 0.01f * a;     // leaky_relu
            att_lds[n] = a;
        }
    }
    __syncthreads();

    // ---- softmax over N=64 in wave 0 ----
    if (tid < 64) {
        float x = att_lds[tid];
        float m = x;
        #pragma unroll
        for (int o = 32; o; o >>= 1) m = fmaxf(m, __shfl_xor(m, o));
        float e = __expf(x - m);
        float s = e;
        #pragma unroll
        for (int o = 32; o; o >>= 1) s += __shfl_xor(s, o);
        float r = e / s;
        if (r == 0.015625f) r = 0.0f;           // masked_fill(att==1/N, 0)
        att_lds[tid] = r;
    }
    __syncthreads();

    // ---- agg[d] = sum_n att[n]*v[n,d], direct from global, 2 n-halves ----
    // lane d reads v[n*KV+d]: 100 consecutive floats per n -> coalesced.
    if (tid < 200) {
        const int half = tid / 100;
        const int d    = tid - half * 100;
        const float* vcol = v + (size_t)be * (N * KV) + d;
        float a = 0.f;
        #pragma unroll
        for (int i = 0; i < 32; i++) {
            int nn = half * 32 + i;
            a += att_lds[nn] * vcol[(size_t)nn * KV];
        }
        part_lds[half][d] = a;
    }
    __syncthreads();

    if (tid < KV) agg_lds[tid] = part_lds[0][tid] + part_lds[1][tid];
    __syncthreads();

    // ---- out[be][i] = sum_d agg[d] * W_vT[d][i]  (W_vT L2-resident) ----
    if (tid < KV) {
        float acc = 0.f;
        #pragma unroll 4
        for (int d = 0; d < KV; d++)
            acc += agg_lds[d] * W_vT[d * KV + tid];
        out[(size_t)be * KV + tid] = acc;
    }
}

extern "C" void kernel_launch(void* const* d_in, const int* in_sizes, int n_in,
                              void* d_out, int out_size, void* d_ws, size_t ws_size,
                              hipStream_t stream) {
    // setup_inputs order: input_ent, q, k, v, W_q, b_q, W_kv, W_v
    const float* q    = (const float*)d_in[1];
    const float* k    = (const float*)d_in[2];
    const float* v    = (const float*)d_in[3];
    const float* W_q  = (const float*)d_in[4];
    const float* b_q  = (const float*)d_in[5];
    const float* W_kv = (const float*)d_in[6];
    const float* W_v  = (const float*)d_in[7];
    float* out  = (float*)d_out;

    float* Qk   = (float*)d_ws;          // B*KV   = 3200 floats
    float* W_vT = Qk + B * KV;           // KV*KV  = 10000 floats

    prep_kernel<<<B + 1, 256, 0, stream>>>(q, W_q, b_q, W_kv, W_v, Qk, W_vT);
    attn_kernel<<<B * E, 256, 0, stream>>>(k, v, Qk, W_vT, out);
}